// Round 8
// baseline (1035.000 us; speedup 1.0000x reference)
//
#include <hip/hip_runtime.h>
#include <hip/hip_bf16.h>

typedef __hip_bfloat16 bf16;
typedef __attribute__((ext_vector_type(8))) short short8;
typedef __attribute__((ext_vector_type(8))) __bf16 bf16x8;
typedef __attribute__((ext_vector_type(4))) float f32x4;

#define BN 20736      // 256*81
#define NNODE 81
#define KNB 20
#define PSTR 200      // P LDS stride (shorts): 400B -> 2-way banks (free)
#define XSTR 104      // xbuf stride (shorts): 208B -> 2-way banks (free)

__device__ inline float bf2f(short s) {
  union { unsigned u; float f; } x; x.u = ((unsigned)(unsigned short)s) << 16; return x.f;
}
__device__ inline short f2bf(float f) {
  __hip_bfloat16 h = __float2bfloat16(f);
  return *reinterpret_cast<short*>(&h);
}
__device__ inline bf16x8 ld8(const bf16* p) {
  return __builtin_bit_cast(bf16x8, *(const short8*)p);
}

// full-width GEMM stage: acc[6] += af(16 rows x K96) @ W[96x96]^T, W streamed from L2
__device__ inline void zacc6(f32x4 acc[6]) {
  #pragma unroll
  for (int nt = 0; nt < 6; ++nt) acc[nt] = (f32x4){0.f, 0.f, 0.f, 0.f};
}
__device__ inline void stage96(const bf16* __restrict__ W, int ldw,
                               const bf16x8 af[3], int lr, int lq, f32x4 acc[6]) {
  #pragma unroll
  for (int nt = 0; nt < 6; ++nt)
    #pragma unroll
    for (int ks = 0; ks < 3; ++ks)
      acc[nt] = __builtin_amdgcn_mfma_f32_16x16x32_bf16(
          ld8(&W[(size_t)(nt * 16 + lr) * ldw + ks * 32 + lq * 8]), // B-frag: col n, k
          acc[nt], acc[nt], 0, 0, 0) , acc[nt]; // placeholder (rewritten below)
}
// NOTE: the above trick doesn't work in C++; real implementation below as macro-like fn:
__device__ inline void stage96r(const bf16* __restrict__ W, int ldw,
                                const bf16x8 af[3], int lr, int lq, f32x4 acc[6]) {
  #pragma unroll
  for (int nt = 0; nt < 6; ++nt)
    #pragma unroll
    for (int ks = 0; ks < 3; ++ks) {
      bf16x8 wf = ld8(&W[(size_t)(nt * 16 + lr) * ldw + ks * 32 + lq * 8]);
      acc[nt] = __builtin_amdgcn_mfma_f32_16x16x32_bf16(af[ks], wf, acc[nt], 0, 0, 0);
    }
}
// acc (row=lq*4+r, col=nt*16+lr) -> per-wave xbuf bf16, with epilogue
__device__ inline void acc2xb(short* xw, const f32x4 acc[6], int lr, int lq,
                              const float* __restrict__ bias, float bscale,
                              const f32x4* xres, int act) {
  #pragma unroll
  for (int nt = 0; nt < 6; ++nt) {
    float bv = bias ? bscale * bias[nt * 16 + lr] : 0.f;
    #pragma unroll
    for (int r = 0; r < 4; ++r) {
      float v = acc[nt][r] + bv;
      if (xres) v += xres[nt][r];
      if (act) v = fmaxf(v, 0.f);
      xw[(lq * 4 + r) * XSTR + nt * 16 + lr] = f2bf(v);
    }
  }
}
__device__ inline void xb2frag(const short* xw, int lr, int lq, bf16x8 af[3]) {
  #pragma unroll
  for (int ks = 0; ks < 3; ++ks)
    af[ks] = __builtin_bit_cast(bf16x8, *(const short8*)&xw[lr * XSTR + ks * 32 + lq * 8]);
}

// ================= weight prep =================
__global__ __launch_bounds__(256) void prep_k(
    const float* in_w1, const float* in_w2, const float* f_w1, const float* f_w2,
    const float* g_w1, const float* g_w2, const float* r_w0, const float* r_w1,
    const float* r_w2, const float* wih, const float* whh, const float* g_w0,
    const float* f_w0, const float* in_w0,
    bf16* inw1b, bf16* inw2b, bf16* fw1b, bf16* fw2b,
    bf16* gw1b, bf16* gw2b, bf16* rw0b, bf16* rw1b,
    bf16* rw2b, bf16* wihb, bf16* whhb, bf16* gw0b,
    bf16* wfnb, bf16* w0pb)
{
  int idx = blockIdx.x * 256 + threadIdx.x;
  int y = blockIdx.y;
  const float* src = nullptr; bf16* dst = nullptr; int cnt = 0;
  switch (y) {
    case 0:  src = in_w1; dst = inw1b; cnt = 9216;  break;
    case 1:  src = in_w2; dst = inw2b; cnt = 9216;  break;
    case 2:  src = f_w1;  dst = fw1b;  cnt = 9216;  break;
    case 3:  src = f_w2;  dst = fw2b;  cnt = 9216;  break;
    case 4:  src = g_w1;  dst = gw1b;  cnt = 9216;  break;
    case 5:  src = g_w2;  dst = gw2b;  cnt = 9216;  break;
    case 6:  src = r_w0;  dst = rw0b;  cnt = 9216;  break;
    case 7:  src = r_w1;  dst = rw1b;  cnt = 9216;  break;
    case 8:  src = r_w2;  dst = rw2b;  cnt = 864;   break;
    case 9:  src = wih;   dst = wihb;  cnt = 36864; break;
    case 10: src = whh;   dst = whhb;  cnt = 36864; break;
    case 11: src = g_w0;  dst = gw0b;  cnt = 18432; break;
    case 12: {  // wfn[192][96]: rows 0-95 = f_w0[n,0:96]; 96-191 = f_w0[n-96,96:192]
      if (idx < 18432) {
        int n = idx / 96, k = idx - n * 96;
        float v = (n < 96) ? f_w0[n * 192 + k] : f_w0[(n - 96) * 192 + 96 + k];
        wfnb[idx] = __float2bfloat16(v);
      }
      return;
    }
    default: {  // w0p[96][32] zero-padded in_w0 (96x16)
      if (idx < 3072) {
        int n = idx >> 5, k = idx & 31;
        w0pb[idx] = __float2bfloat16(k < 16 ? in_w0[n * 16 + k] : 0.f);
      }
      return;
    }
  }
  if (idx < cnt) dst[idx] = __float2bfloat16(src[idx]);
}

// ================= mega kernel: one block per batch sample =================
__global__ __launch_bounds__(384, 1) void mega_k(
    const float* __restrict__ embed, const int* __restrict__ grids,
    const int* __restrict__ edges,
    const bf16* __restrict__ w0pb, const float* __restrict__ in_b0,
    const bf16* __restrict__ inw1b, const float* __restrict__ in_b1,
    const bf16* __restrict__ inw2b, const float* __restrict__ in_b2,
    const bf16* __restrict__ gw0b, const float* __restrict__ g_b0,
    const bf16* __restrict__ wfnb, const float* __restrict__ f_b0,
    const bf16* __restrict__ fw1b, const float* __restrict__ f_b1,
    const bf16* __restrict__ fw2b, const float* __restrict__ f_b2,
    const bf16* __restrict__ gw1b, const float* __restrict__ g_b1,
    const bf16* __restrict__ gw2b, const float* __restrict__ g_b2,
    const bf16* __restrict__ wihb, const bf16* __restrict__ whhb,
    const float* __restrict__ bih, const float* __restrict__ bhh,
    const bf16* __restrict__ rw0b, const float* __restrict__ r_b0,
    const bf16* __restrict__ rw1b, const float* __restrict__ r_b1,
    const bf16* __restrict__ rw2b, const float* __restrict__ r_b2,
    float* __restrict__ c, float* __restrict__ outp, int iters)
{
  __shared__ short Pl[96 * PSTR];          // 38.4 KB: P rows (node x 192)
  __shared__ short xb_all[6][16 * XSTR];   // 20.0 KB: per-wave transpose buffers
  const int s = blockIdx.x;
  const int t = threadIdx.x, w = t >> 6, lane = t & 63, lr = lane & 15, lq = lane >> 4;
  short* xw = xb_all[w];
  const int gbase = s * NNODE;
  const int nodeA = w * 16 + lr;           // A-frag row node for this lane

  f32x4 acc[6];
  bf16x8 af[3], hf[3];
  f32x4 xga[6];                            // Xg (incl g_b0) in ACC layout, persistent

  // ---------- prologue: emb -> X -> Xg, P0 ----------
  {
    short8 es = {0, 0, 0, 0, 0, 0, 0, 0};
    if (nodeA < NNODE && lq < 2) {
      int g = grids[gbase + nodeA];
      #pragma unroll
      for (int j = 0; j < 8; ++j) es[j] = f2bf(embed[g * 16 + lq * 8 + j]);
    }
    bf16x8 aemb = __builtin_bit_cast(bf16x8, es);
    zacc6(acc);
    #pragma unroll
    for (int nt = 0; nt < 6; ++nt) {
      bf16x8 wf = ld8(&w0pb[(size_t)(nt * 16 + lr) * 32 + lq * 8]);
      acc[nt] = __builtin_amdgcn_mfma_f32_16x16x32_bf16(aemb, wf, acc[nt], 0, 0, 0);
    }
    acc2xb(xw, acc, lr, lq, in_b0, 1.f, nullptr, 1); xb2frag(xw, lr, lq, af);
    zacc6(acc); stage96r(inw1b, 96, af, lr, lq, acc);
    acc2xb(xw, acc, lr, lq, in_b1, 1.f, nullptr, 1); xb2frag(xw, lr, lq, af);
    zacc6(acc); stage96r(inw2b, 96, af, lr, lq, acc);
    acc2xb(xw, acc, lr, lq, in_b2, 1.f, nullptr, 0); xb2frag(xw, lr, lq, hf);  // hf = X frags
    // Xg = X @ g_w0[:, :96]^T + g_b0  (kept in ACC-layout regs)
    zacc6(acc); stage96r(gw0b, 192, hf, lr, lq, acc);
    #pragma unroll
    for (int nt = 0; nt < 6; ++nt) {
      float bv = g_b0[nt * 16 + lr];
      #pragma unroll
      for (int r = 0; r < 4; ++r) xga[nt][r] = acc[nt][r] + bv;
    }
    // P0 = X @ wfn^T (+f_b0 on first half) -> Pl (direct ACC-layout stores)
    #pragma unroll
    for (int ph = 0; ph < 2; ++ph) {
      zacc6(acc); stage96r(wfnb + (size_t)ph * 96 * 96, 96, hf, lr, lq, acc);
      #pragma unroll
      for (int nt = 0; nt < 6; ++nt) {
        float bv = ph == 0 ? f_b0[nt * 16 + lr] : 0.f;
        #pragma unroll
        for (int r = 0; r < 4; ++r) {
          int node = w * 16 + lq * 4 + r;
          Pl[node * PSTR + ph * 96 + nt * 16 + lr] = f2bf(acc[nt][r] + bv);
        }
      }
    }
  }

  for (int it = 0; it < iters; ++it) {
    __syncthreads();   // all P writes visible before edge reads

    // ---------- edge: S for this wave's 16 nodes -> xb ----------
    #pragma unroll 1
    for (int gl = 0; gl < 4; ++gl) {
      const int grp = w * 4 + gl;
      bf16x8 zf[5][3];
      #pragma unroll
      for (int mt = 0; mt < 5; ++mt) {
        int zrow = mt * 16 + lr;
        int p = zrow / 20, j = zrow - p * 20;
        int i = grp * 4 + p;
        int e = (i < NNODE) ? edges[i * KNB + j] : 0;
        #pragma unroll
        for (int ks = 0; ks < 3; ++ks) {
          short8 a8 = *(const short8*)&Pl[i * PSTR + ks * 32 + lq * 8];
          short8 n8 = *(const short8*)&Pl[e * PSTR + 96 + ks * 32 + lq * 8];
          short8 z;
          #pragma unroll
          for (int q = 0; q < 8; ++q)
            z[q] = f2bf(fmaxf(bf2f(a8[q]) + bf2f(n8[q]), 0.f));
          zf[mt][ks] = __builtin_bit_cast(bf16x8, z);
        }
      }
      #pragma unroll
      for (int half = 0; half < 2; ++half) {
        f32x4 ea[5][3];
        #pragma unroll
        for (int mt = 0; mt < 5; ++mt)
          #pragma unroll
          for (int nt = 0; nt < 3; ++nt) ea[mt][nt] = (f32x4){0.f, 0.f, 0.f, 0.f};
        #pragma unroll
        for (int nt = 0; nt < 3; ++nt)
          #pragma unroll
          for (int ks = 0; ks < 3; ++ks) {
            bf16x8 wf = ld8(&fw1b[(size_t)(half * 48 + nt * 16 + lr) * 96 + ks * 32 + lq * 8]);
            #pragma unroll
            for (int mt = 0; mt < 5; ++mt)
              ea[mt][nt] = __builtin_amdgcn_mfma_f32_16x16x32_bf16(zf[mt][ks], wf, ea[mt][nt], 0, 0, 0);
          }
        float b1v[3];
        #pragma unroll
        for (int nt = 0; nt < 3; ++nt) b1v[nt] = f_b1[half * 48 + nt * 16 + lr];
        float na[4][3];
        #pragma unroll
        for (int pp = 0; pp < 4; ++pp)
          #pragma unroll
          for (int nt = 0; nt < 3; ++nt) na[pp][nt] = 0.f;
        #pragma unroll
        for (int mt = 0; mt < 5; ++mt)
          #pragma unroll
          for (int nt = 0; nt < 3; ++nt)
            #pragma unroll
            for (int r = 0; r < 4; ++r) {
              int row = mt * 16 + lq * 4 + r;
              int p = row / 20;
              float v = fmaxf(ea[mt][nt][r] + b1v[nt], 0.f);
              #pragma unroll
              for (int pp = 0; pp < 4; ++pp) na[pp][nt] += (p == pp) ? v : 0.f;
            }
        #pragma unroll
        for (int pp = 0; pp < 4; ++pp)
          #pragma unroll
          for (int nt = 0; nt < 3; ++nt) {
            float v = na[pp][nt];
            v += __shfl_xor(v, 16, 64);
            v += __shfl_xor(v, 32, 64);
            if (lq == 0)
              xw[(gl * 4 + pp) * XSTR + half * 48 + nt * 16 + lr] = f2bf(v);
          }
      }
    }

    // ---------- M = S @ f_w2^T + 20*f_b2 ----------
    xb2frag(xw, lr, lq, af);
    zacc6(acc); stage96r(fw2b, 96, af, lr, lq, acc);
    acc2xb(xw, acc, lr, lq, f_b2, (float)KNB, nullptr, 0); xb2frag(xw, lr, lq, af);
    // z1 = relu(M @ g_w0[:,96:]^T + Xg)
    zacc6(acc); stage96r(gw0b + 96, 192, af, lr, lq, acc);
    acc2xb(xw, acc, lr, lq, nullptr, 0.f, xga, 1); xb2frag(xw, lr, lq, af);
    // z2 = relu(z1 @ g_w1^T + g_b1)
    zacc6(acc); stage96r(gw1b, 96, af, lr, lq, acc);
    acc2xb(xw, acc, lr, lq, g_b1, 1.f, nullptr, 1); xb2frag(xw, lr, lq, af);
    // gin = z2 @ g_w2^T + g_b2
    zacc6(acc); stage96r(gw2b, 96, af, lr, lq, acc);
    acc2xb(xw, acc, lr, lq, g_b2, 1.f, nullptr, 0);
    bf16x8 gf[3]; xb2frag(xw, lr, lq, gf);

    // ---------- gates + LSTM cell (2 col-half passes) ----------
    #pragma unroll
    for (int half = 0; half < 2; ++half) {
      f32x4 ga[4][3];
      #pragma unroll
      for (int g4 = 0; g4 < 4; ++g4)
        #pragma unroll
        for (int nt = 0; nt < 3; ++nt) ga[g4][nt] = (f32x4){0.f, 0.f, 0.f, 0.f};
      #pragma unroll
      for (int g4 = 0; g4 < 4; ++g4)
        #pragma unroll
        for (int nt = 0; nt < 3; ++nt) {
          size_t nrow = (size_t)(g4 * 96 + half * 48 + nt * 16 + lr) * 96;
          #pragma unroll
          for (int ks = 0; ks < 3; ++ks) {
            bf16x8 wi = ld8(&wihb[nrow + ks * 32 + lq * 8]);
            ga[g4][nt] = __builtin_amdgcn_mfma_f32_16x16x32_bf16(gf[ks], wi, ga[g4][nt], 0, 0, 0);
            bf16x8 wh = ld8(&whhb[nrow + ks * 32 + lq * 8]);
            ga[g4][nt] = __builtin_amdgcn_mfma_f32_16x16x32_bf16(hf[ks], wh, ga[g4][nt], 0, 0, 0);
          }
        }
      #pragma unroll
      for (int nt = 0; nt < 3; ++nt) {
        int col = half * 48 + nt * 16 + lr;
        float bvi = bih[col] + bhh[col];
        float bvf = bih[96 + col] + bhh[96 + col];
        float bvg = bih[192 + col] + bhh[192 + col];
        float bvo = bih[288 + col] + bhh[288 + col];
        #pragma unroll
        for (int r = 0; r < 4; ++r) {
          int node = w * 16 + lq * 4 + r;
          float gi = ga[0][nt][r] + bvi;
          float gfv = ga[1][nt][r] + bvf;
          float gg = ga[2][nt][r] + bvg;
          float go = ga[3][nt][r] + bvo;
          float si = 1.f / (1.f + expf(-gi));
          float sf = 1.f / (1.f + expf(-gfv));
          float so = 1.f / (1.f + expf(-go));
          float tg = tanhf(gg);
          float ho;
          if (node < NNODE) {
            size_t idx = (size_t)(gbase + node) * 96 + col;
            float cn = sf * c[idx] + si * tg;
            c[idx] = cn;
            ho = so * tanhf(cn);
          } else ho = 0.f;
          xw[(lq * 4 + r) * XSTR + col] = f2bf(ho);
        }
      }
    }
    xb2frag(xw, lr, lq, hf);   // hf = new H frags

    __syncthreads();           // all edge reads of old P done; safe to rebuild P

    // ---------- P = H @ wfn^T (+f_b0) ----------
    #pragma unroll
    for (int ph = 0; ph < 2; ++ph) {
      zacc6(acc); stage96r(wfnb + (size_t)ph * 96 * 96, 96, hf, lr, lq, acc);
      #pragma unroll
      for (int nt = 0; nt < 6; ++nt) {
        float bv = ph == 0 ? f_b0[nt * 16 + lr] : 0.f;
        #pragma unroll
        for (int r = 0; r < 4; ++r) {
          int node = w * 16 + lq * 4 + r;
          Pl[node * PSTR + ph * 96 + nt * 16 + lr] = f2bf(acc[nt][r] + bv);
        }
      }
    }

    // ---------- r-MLP -> out ----------
    zacc6(acc); stage96r(rw0b, 96, hf, lr, lq, acc);
    acc2xb(xw, acc, lr, lq, r_b0, 1.f, nullptr, 1); xb2frag(xw, lr, lq, af);
    zacc6(acc); stage96r(rw1b, 96, af, lr, lq, acc);
    acc2xb(xw, acc, lr, lq, r_b1, 1.f, nullptr, 1); xb2frag(xw, lr, lq, af);
    bf16x8 w9[3];
    #pragma unroll
    for (int ks = 0; ks < 3; ++ks) {
      short8 ws9 = {0, 0, 0, 0, 0, 0, 0, 0};
      if (lr < 9) ws9 = *(const short8*)&rw2b[(size_t)lr * 96 + ks * 32 + lq * 8];
      w9[ks] = __builtin_bit_cast(bf16x8, ws9);
    }
    f32x4 a9 = (f32x4){0.f, 0.f, 0.f, 0.f};
    #pragma unroll
    for (int ks = 0; ks < 3; ++ks)
      a9 = __builtin_amdgcn_mfma_f32_16x16x32_bf16(af[ks], w9[ks], a9, 0, 0, 0);
    if (lr < 9) {
      float bb = r_b2[lr];
      #pragma unroll
      for (int r = 0; r < 4; ++r) {
        int node = w * 16 + lq * 4 + r;
        if (node < NNODE)
          outp[(size_t)it * BN * 9 + (size_t)(gbase + node) * 9 + lr] = a9[r] + bb;
      }
    }
  }
}

// ================= host side =================
extern "C" void kernel_launch(void* const* d_in, const int* in_sizes, int n_in,
                              void* d_out, int out_size, void* d_ws, size_t ws_size,
                              hipStream_t stream) {
  const float* embed   = (const float*)d_in[0];
  const float* in_w0   = (const float*)d_in[1];
  const float* in_b0   = (const float*)d_in[2];
  const float* in_w1   = (const float*)d_in[3];
  const float* in_b1   = (const float*)d_in[4];
  const float* in_w2   = (const float*)d_in[5];
  const float* in_b2   = (const float*)d_in[6];
  const float* f_w0    = (const float*)d_in[7];
  const float* f_b0    = (const float*)d_in[8];
  const float* f_w1    = (const float*)d_in[9];
  const float* f_b1    = (const float*)d_in[10];
  const float* f_w2    = (const float*)d_in[11];
  const float* f_b2    = (const float*)d_in[12];
  const float* g_w0    = (const float*)d_in[13];
  const float* g_b0    = (const float*)d_in[14];
  const float* g_w1    = (const float*)d_in[15];
  const float* g_b1    = (const float*)d_in[16];
  const float* g_w2    = (const float*)d_in[17];
  const float* g_b2    = (const float*)d_in[18];
  const float* wih     = (const float*)d_in[19];
  const float* whh     = (const float*)d_in[20];
  const float* bih     = (const float*)d_in[21];
  const float* bhh     = (const float*)d_in[22];
  const float* r_w0    = (const float*)d_in[23];
  const float* r_b0    = (const float*)d_in[24];
  const float* r_w1    = (const float*)d_in[25];
  const float* r_b1    = (const float*)d_in[26];
  const float* r_w2    = (const float*)d_in[27];
  const float* r_b2    = (const float*)d_in[28];
  const float* c0      = (const float*)d_in[29];
  const int*   grids   = (const int*)d_in[30];
  const int*   edges   = (const int*)d_in[31];

  float* out = (float*)d_out;
  const int iters = out_size / (BN * 9);   // = 4

  float* c    = (float*)d_ws;                        // BN*96 f32
  bf16* inw1b = (bf16*)(c + (size_t)BN * 96);
  bf16* inw2b = inw1b + 9216;
  bf16* fw1b  = inw2b + 9216;
  bf16* fw2b  = fw1b + 9216;
  bf16* gw1b  = fw2b + 9216;
  bf16* gw2b  = gw1b + 9216;
  bf16* rw0b  = gw2b + 9216;
  bf16* rw1b  = rw0b + 9216;
  bf16* rw2b  = rw1b + 9216;                         // 864
  bf16* wihb  = rw2b + 864;                          // 36864
  bf16* whhb  = wihb + 36864;
  bf16* gw0b  = whhb + 36864;                        // 18432
  bf16* wfnb  = gw0b + 18432;                        // 18432
  bf16* w0pb  = wfnb + 18432;                        // 3072

  prep_k<<<dim3(144, 14), 256, 0, stream>>>(
      in_w1, in_w2, f_w1, f_w2, g_w1, g_w2, r_w0, r_w1, r_w2, wih, whh, g_w0,
      f_w0, in_w0,
      inw1b, inw2b, fw1b, fw2b, gw1b, gw2b, rw0b, rw1b, rw2b, wihb, whhb, gw0b,
      wfnb, w0pb);
  hipMemcpyAsync(c, c0, (size_t)BN * 96 * sizeof(float), hipMemcpyDeviceToDevice, stream);

  mega_k<<<256, 384, 0, stream>>>(
      embed, grids, edges,
      w0pb, in_b0, inw1b, in_b1, inw2b, in_b2,
      gw0b, g_b0, wfnb, f_b0, fw1b, f_b1, fw2b, f_b2,
      gw1b, g_b1, gw2b, g_b2,
      wihb, whhb, bih, bhh,
      rw0b, r_b0, rw1b, r_b1, rw2b, r_b2,
      c, out, iters);
}

// Round 9
// 336.539 us; speedup vs baseline: 3.0754x; 3.0754x over previous
//
#include <hip/hip_runtime.h>
#include <hip/hip_bf16.h>

typedef __hip_bfloat16 bf16;
typedef __attribute__((ext_vector_type(8))) short short8;
typedef __attribute__((ext_vector_type(8))) __bf16 bf16x8;
typedef __attribute__((ext_vector_type(4))) float f32x4;

#define BN 20736      // 256*81
#define NNODE 81
#define KNB 20

__device__ inline float bf2f(short s) {
  union { unsigned u; float f; } x; x.u = ((unsigned)(unsigned short)s) << 16; return x.f;
}
__device__ inline short f2bf(float f) {
  __hip_bfloat16 h = __float2bfloat16(f);
  return *reinterpret_cast<short*>(&h);
}
__device__ inline bf16x8 ld8(const bf16* p) {
  return __builtin_bit_cast(bf16x8, *(const short8*)p);
}

// ---------- col-split helpers: wave owns 16 rows x 48 cols (n0 = ch*48) ----------
__device__ inline void zacc3(f32x4 acc[3]) {
  #pragma unroll
  for (int nt = 0; nt < 3; ++nt) acc[nt] = (f32x4){0.f, 0.f, 0.f, 0.f};
}
__device__ inline void load_w48(const bf16* __restrict__ W, int ldw, int n0, int lr, int lq,
                                bf16x8 wf[3][3]) {
  #pragma unroll
  for (int nt = 0; nt < 3; ++nt)
    #pragma unroll
    for (int ks = 0; ks < 3; ++ks)
      wf[nt][ks] = ld8(&W[(size_t)(n0 + nt * 16 + lr) * ldw + ks * 32 + lq * 8]);
}
__device__ inline void gemm48(const bf16x8 af[3], const bf16x8 wf[3][3], f32x4 acc[3]) {
  #pragma unroll
  for (int ks = 0; ks < 3; ++ks)
    #pragma unroll
    for (int nt = 0; nt < 3; ++nt)
      acc[nt] = __builtin_amdgcn_mfma_f32_16x16x32_bf16(af[ks], wf[nt][ks], acc[nt], 0, 0, 0);
}
__device__ inline void acc_store_cs(float* xw, const f32x4 acc[3], int lr, int lq, int n0) {
  #pragma unroll
  for (int nt = 0; nt < 3; ++nt)
    #pragma unroll
    for (int r = 0; r < 4; ++r)
      xw[(lq * 4 + r) * 100 + n0 + nt * 16 + lr] = acc[nt][r];
}
__device__ inline void xbuf_frag(const float* xw, int lr, int lq,
                                 const float* __restrict__ bias, float bscale,
                                 const bf16* __restrict__ residRow, int act,
                                 bf16x8 af[3]) {
  #pragma unroll
  for (int ks = 0; ks < 3; ++ks) {
    const int c0 = ks * 32 + lq * 8;
    float4 x0 = *(const float4*)&xw[lr * 100 + c0];
    float4 x1 = *(const float4*)&xw[lr * 100 + c0 + 4];
    float xv[8] = {x0.x, x0.y, x0.z, x0.w, x1.x, x1.y, x1.z, x1.w};
    if (bias) {
      float4 b0 = *(const float4*)&bias[c0];
      float4 b1 = *(const float4*)&bias[c0 + 4];
      float bv[8] = {b0.x, b0.y, b0.z, b0.w, b1.x, b1.y, b1.z, b1.w};
      #pragma unroll
      for (int j = 0; j < 8; ++j) xv[j] += bscale * bv[j];
    }
    if (residRow) {
      short8 r8 = *(const short8*)&residRow[c0];
      #pragma unroll
      for (int j = 0; j < 8; ++j) xv[j] += bf2f(r8[j]);
    }
    short8 o;
    #pragma unroll
    for (int j = 0; j < 8; ++j) {
      float v = xv[j];
      if (act) v = fmaxf(v, 0.f);
      o[j] = f2bf(v);
    }
    af[ks] = __builtin_bit_cast(bf16x8, o);
  }
}
__device__ inline void store_frag(bf16* dst, int lq, const bf16x8 af[3]) {
  #pragma unroll
  for (int ks = 0; ks < 3; ++ks)
    *(short8*)&dst[ks * 32 + lq * 8] = __builtin_bit_cast(short8, af[ks]);
}

// ================= prologue: convert/build all weights =================
__global__ __launch_bounds__(256) void prep_k(
    const float* in_w1, const float* in_w2, const float* f_w1, const float* f_w2,
    const float* g_w1, const float* g_w2, const float* r_w0, const float* r_w1,
    const float* r_w2, const float* wih, const float* whh, const float* g_w0,
    const float* f_w0, const float* in_w0, const float* f_b0,
    bf16* inw1b, bf16* inw2b, bf16* fw1b, bf16* fw2b,
    bf16* gw1b, bf16* gw2b, bf16* rw0b, bf16* rw1b,
    bf16* rw2b, bf16* wihb, bf16* whhb, bf16* gw0b,
    bf16* wfnb, bf16* w0pb, float* bias_fn)
{
  int idx = blockIdx.x * 256 + threadIdx.x;
  int y = blockIdx.y;
  const float* src = nullptr; bf16* dst = nullptr; int cnt = 0;
  switch (y) {
    case 0:  src = in_w1; dst = inw1b; cnt = 9216;  break;
    case 1:  src = in_w2; dst = inw2b; cnt = 9216;  break;
    case 2:  src = f_w1;  dst = fw1b;  cnt = 9216;  break;
    case 3:  src = f_w2;  dst = fw2b;  cnt = 9216;  break;
    case 4:  src = g_w1;  dst = gw1b;  cnt = 9216;  break;
    case 5:  src = g_w2;  dst = gw2b;  cnt = 9216;  break;
    case 6:  src = r_w0;  dst = rw0b;  cnt = 9216;  break;
    case 7:  src = r_w1;  dst = rw1b;  cnt = 9216;  break;
    case 8:  src = r_w2;  dst = rw2b;  cnt = 864;   break;
    case 9:  src = wih;   dst = wihb;  cnt = 36864; break;
    case 10: src = whh;   dst = whhb;  cnt = 36864; break;
    case 11: src = g_w0;  dst = gw0b;  cnt = 18432; break;
    case 12: {
      if (idx < 18432) {
        int n = idx / 96, k = idx - n * 96;
        float v = (n < 96) ? f_w0[n * 192 + k] : f_w0[(n - 96) * 192 + 96 + k];
        wfnb[idx] = __float2bfloat16(v);
      }
      return;
    }
    case 13: {
      if (idx < 3072) {
        int n = idx >> 5, k = idx & 31;
        w0pb[idx] = __float2bfloat16(k < 16 ? in_w0[n * 16 + k] : 0.f);
      }
      return;
    }
    default: {
      if (idx < 192) bias_fn[idx] = (idx < 96) ? f_b0[idx] : 0.f;
      return;
    }
  }
  if (idx < cnt) dst[idx] = __float2bfloat16(src[idx]);
}

__global__ __launch_bounds__(256) void embed_k(const float* __restrict__ embed,
                                               const int* __restrict__ grids,
                                               bf16* __restrict__ emb) {
  int idx = blockIdx.x * 256 + threadIdx.x;
  if (idx >= BN * 32) return;
  int r = idx >> 5, k = idx & 31;
  emb[idx] = __float2bfloat16(k < 16 ? embed[grids[r] * 16 + k] : 0.f);
}

// ================= fused input chain (col-split): emb -> X -> {Xg, P0} =================
__global__ __launch_bounds__(256) void fused_in_k(
    const bf16* __restrict__ emb, const bf16* __restrict__ w0pb, const float* __restrict__ in_b0,
    const bf16* __restrict__ inw1b, const float* __restrict__ in_b1,
    const bf16* __restrict__ inw2b, const float* __restrict__ in_b2,
    const bf16* __restrict__ gw0b, const float* __restrict__ g_b0,
    const bf16* __restrict__ wfnb, const float* __restrict__ bias_fn,
    bf16* __restrict__ X, bf16* __restrict__ Xg, bf16* __restrict__ P)
{
  __shared__ float xbuf[2][2][1600];
  const int t = threadIdx.x, w = t >> 6, lane = t & 63, lr = lane & 15, lq = lane >> 4;
  const int mh = w >> 1, ch = w & 1, n0 = ch * 48;
  const int m0 = blockIdx.x * 32 + mh * 16;
  float* x0 = xbuf[0][mh];
  float* x1 = xbuf[1][mh];
  bf16x8 wf[3][3]; f32x4 acc[3]; bf16x8 af[3];

  bf16x8 a0 = ld8(&emb[(size_t)(m0 + lr) * 32 + lq * 8]);
  #pragma unroll
  for (int nt = 0; nt < 3; ++nt)
    wf[nt][0] = ld8(&w0pb[(size_t)(n0 + nt * 16 + lr) * 32 + lq * 8]);
  zacc3(acc);
  #pragma unroll
  for (int nt = 0; nt < 3; ++nt)
    acc[nt] = __builtin_amdgcn_mfma_f32_16x16x32_bf16(a0, wf[nt][0], acc[nt], 0, 0, 0);
  acc_store_cs(x0, acc, lr, lq, n0);
  __syncthreads();
  xbuf_frag(x0, lr, lq, in_b0, 1.f, nullptr, 1, af);
  load_w48(inw1b, 96, n0, lr, lq, wf); zacc3(acc); gemm48(af, wf, acc);
  acc_store_cs(x1, acc, lr, lq, n0);
  __syncthreads();
  xbuf_frag(x1, lr, lq, in_b1, 1.f, nullptr, 1, af);
  load_w48(inw2b, 96, n0, lr, lq, wf); zacc3(acc); gemm48(af, wf, acc);
  acc_store_cs(x0, acc, lr, lq, n0);
  __syncthreads();
  bf16x8 xf[3];
  xbuf_frag(x0, lr, lq, in_b2, 1.f, nullptr, 0, xf);
  if (ch == 0) store_frag(&X[(size_t)(m0 + lr) * 96], lq, xf);
  load_w48(gw0b, 192, n0, lr, lq, wf); zacc3(acc); gemm48(xf, wf, acc);
  acc_store_cs(x1, acc, lr, lq, n0);
  __syncthreads();
  xbuf_frag(x1, lr, lq, g_b0, 1.f, nullptr, 0, af);
  if (ch == 0) store_frag(&Xg[(size_t)(m0 + lr) * 96], lq, af);
  #pragma unroll
  for (int ph = 0; ph < 2; ++ph) {
    float* xb = ph ? x1 : x0;
    load_w48(wfnb + (size_t)ph * 96 * 96, 96, n0, lr, lq, wf); zacc3(acc); gemm48(xf, wf, acc);
    acc_store_cs(xb, acc, lr, lq, n0);
    __syncthreads();
    xbuf_frag(xb, lr, lq, bias_fn + ph * 96, 1.f, nullptr, 0, af);
    if (ch == 0) store_frag(&P[(size_t)(m0 + lr) * 192 + ph * 96], lq, af);
  }
}

// ================= edge kernel (unchanged from R7): LDS Z + fused M tail =================
__global__ __launch_bounds__(256) void edge_k(
    const bf16* __restrict__ P, const bf16* __restrict__ w1bf,
    const float* __restrict__ b1, const int* __restrict__ edges,
    const bf16* __restrict__ fw2b, const float* __restrict__ f_b2,
    bf16* __restrict__ M)
{
  __shared__ short zs[160 * 104];
  __shared__ short sbuf[16 * 104];
  const int t = threadIdx.x;
  const int ng0 = blockIdx.x * 2;
  for (int i = t; i < 8 * 104; i += 256) sbuf[(8 + i / 104) * 104 + (i % 104)] = 0;
  for (int cc = t; cc < 160 * 12; cc += 256) {
    int zrow = cc / 12, c8 = cc - zrow * 12;
    int g = zrow >= 80 ? 1 : 0;
    int row = zrow - g * 80;
    int p = row / 20, j = row - p * 20;
    int gr = (ng0 + g) * 4 + p;
    int b = gr / NNODE, i = gr - b * NNODE;
    int e = edges[i * KNB + j];
    short8 a8 = *(const short8*)&P[(size_t)gr * 192 + c8 * 8];
    short8 n8 = *(const short8*)&P[((size_t)b * NNODE + e) * 192 + 96 + c8 * 8];
    short8 z;
    #pragma unroll
    for (int q = 0; q < 8; ++q)
      z[q] = f2bf(fmaxf(bf2f(a8[q]) + bf2f(n8[q]), 0.f));
    *(short8*)&zs[zrow * 104 + c8 * 8] = z;
  }
  __syncthreads();

  const int w = t >> 6, lane = t & 63, lr = lane & 15, lq = lane >> 4;
  const int g = w >> 1, ch = w & 1, n0 = ch * 48, zb = g * 80;

  bf16x8 wf[3][3];
  #pragma unroll
  for (int nt = 0; nt < 3; ++nt)
    #pragma unroll
    for (int ks = 0; ks < 3; ++ks)
      wf[nt][ks] = ld8(&w1bf[(size_t)(n0 + nt * 16 + lr) * 96 + ks * 32 + lq * 8]);

  f32x4 acc[5][3];
  #pragma unroll
  for (int mt = 0; mt < 5; ++mt)
    #pragma unroll
    for (int nt = 0; nt < 3; ++nt) acc[mt][nt] = (f32x4){0.f, 0.f, 0.f, 0.f};

  #pragma unroll
  for (int ks = 0; ks < 3; ++ks) {
    const int koff = ks * 32 + lq * 8;
    #pragma unroll
    for (int mt = 0; mt < 5; ++mt) {
      bf16x8 af = __builtin_bit_cast(bf16x8, *(const short8*)&zs[(zb + mt * 16 + lr) * 104 + koff]);
      #pragma unroll
      for (int nt = 0; nt < 3; ++nt)
        acc[mt][nt] = __builtin_amdgcn_mfma_f32_16x16x32_bf16(af, wf[nt][ks], acc[mt][nt], 0, 0, 0);
    }
  }

  float bv[3];
  #pragma unroll
  for (int nt = 0; nt < 3; ++nt) bv[nt] = b1[n0 + nt * 16 + lr];
  float nodeacc[4][3];
  #pragma unroll
  for (int pp = 0; pp < 4; ++pp)
    #pragma unroll
    for (int nt = 0; nt < 3; ++nt) nodeacc[pp][nt] = 0.f;
  #pragma unroll
  for (int mt = 0; mt < 5; ++mt)
    #pragma unroll
    for (int nt = 0; nt < 3; ++nt)
      #pragma unroll
      for (int r = 0; r < 4; ++r) {
        int row = mt * 16 + lq * 4 + r;
        int p = row / 20;
        float v = fmaxf(acc[mt][nt][r] + bv[nt], 0.f);
        #pragma unroll
        for (int pp = 0; pp < 4; ++pp)
          nodeacc[pp][nt] += (p == pp) ? v : 0.f;
      }
  #pragma unroll
  for (int pp = 0; pp < 4; ++pp)
    #pragma unroll
    for (int nt = 0; nt < 3; ++nt) {
      float v = nodeacc[pp][nt];
      v += __shfl_xor(v, 16, 64);
      v += __shfl_xor(v, 32, 64);
      if (lq == 0)
        sbuf[(g * 4 + pp) * 104 + n0 + nt * 16 + lr] = f2bf(v);
    }
  __syncthreads();
  if (w < 2) {
    const int mn0 = w * 48;
    bf16x8 mwf[3][3];
    #pragma unroll
    for (int nt = 0; nt < 3; ++nt)
      #pragma unroll
      for (int ks = 0; ks < 3; ++ks)
        mwf[nt][ks] = ld8(&fw2b[(size_t)(mn0 + nt * 16 + lr) * 96 + ks * 32 + lq * 8]);
    f32x4 macc[3];
    zacc3(macc);
    #pragma unroll
    for (int ks = 0; ks < 3; ++ks) {
      bf16x8 af = __builtin_bit_cast(bf16x8, *(const short8*)&sbuf[lr * 104 + ks * 32 + lq * 8]);
      #pragma unroll
      for (int nt = 0; nt < 3; ++nt)
        macc[nt] = __builtin_amdgcn_mfma_f32_16x16x32_bf16(af, mwf[nt][ks], macc[nt], 0, 0, 0);
    }
    #pragma unroll
    for (int nt = 0; nt < 3; ++nt) {
      int col = mn0 + nt * 16 + lr;
      float bb = (float)KNB * f_b2[col];
      #pragma unroll
      for (int r = 0; r < 4; ++r) {
        int row = lq * 4 + r;
        if (row < 8)
          M[(size_t)(ng0 * 4 + row) * 96 + col] = __float2bfloat16(macc[nt][r] + bb);
      }
    }
  }
}

// ===== fused iteration kernel: M -> z1 -> z2 -> gin -> LSTM -> {P_next, r-MLP->out} =====
__global__ __launch_bounds__(256) void fused_iter_k(
    const bf16* __restrict__ Min,
    const bf16* __restrict__ gw0b, const bf16* __restrict__ Xg,
    const bf16* __restrict__ gw1b, const float* __restrict__ g_b1,
    const bf16* __restrict__ gw2b, const float* __restrict__ g_b2,
    const bf16* __restrict__ Hin,
    const bf16* __restrict__ wihb, const bf16* __restrict__ whhb,
    const float* __restrict__ bih, const float* __restrict__ bhh,
    float* __restrict__ c, bf16* __restrict__ Hout,
    const bf16* __restrict__ wfnb, const float* __restrict__ bias_fn, bf16* __restrict__ P,
    const bf16* __restrict__ rw0b, const float* __restrict__ r_b0,
    const bf16* __restrict__ rw1b, const float* __restrict__ r_b1,
    const bf16* __restrict__ rw2b, const float* __restrict__ r_b2,
    float* __restrict__ outp, int doP)
{
  __shared__ float xbuf[2][2][1600];
  const int t = threadIdx.x, w = t >> 6, lane = t & 63, lr = lane & 15, lq = lane >> 4;
  const int mh = w >> 1, ch = w & 1, n0 = ch * 48;
  const int m0 = blockIdx.x * 32 + mh * 16;
  float* x0 = xbuf[0][mh];
  float* x1 = xbuf[1][mh];
  bf16x8 wf[3][3]; f32x4 acc[3]; bf16x8 af[3];

  // ---- g-MLP ----
  #pragma unroll
  for (int ks = 0; ks < 3; ++ks)
    af[ks] = ld8(&Min[(size_t)(m0 + lr) * 96 + ks * 32 + lq * 8]);
  load_w48(gw0b + 96, 192, n0, lr, lq, wf); zacc3(acc); gemm48(af, wf, acc);
  acc_store_cs(x0, acc, lr, lq, n0);
  __syncthreads();
  xbuf_frag(x0, lr, lq, nullptr, 0.f, &Xg[(size_t)(m0 + lr) * 96], 1, af);
  load_w48(gw1b, 96, n0, lr, lq, wf); zacc3(acc); gemm48(af, wf, acc);
  acc_store_cs(x1, acc, lr, lq, n0);
  __syncthreads();
  xbuf_frag(x1, lr, lq, g_b1, 1.f, nullptr, 1, af);
  load_w48(gw2b, 96, n0, lr, lq, wf); zacc3(acc); gemm48(af, wf, acc);
  acc_store_cs(x0, acc, lr, lq, n0);
  __syncthreads();
  bf16x8 gf[3];
  xbuf_frag(x0, lr, lq, g_b2, 1.f, nullptr, 0, gf);

  // ---- LSTM: all 4 gates for this wave's 48 cols ----
  bf16x8 hin[3];
  #pragma unroll
  for (int ks = 0; ks < 3; ++ks)
    hin[ks] = ld8(&Hin[(size_t)(m0 + lr) * 96 + ks * 32 + lq * 8]);
  f32x4 ga[4][3];
  #pragma unroll
  for (int g4 = 0; g4 < 4; ++g4)
    #pragma unroll
    for (int nt = 0; nt < 3; ++nt) ga[g4][nt] = (f32x4){0.f, 0.f, 0.f, 0.f};
  #pragma unroll
  for (int g4 = 0; g4 < 4; ++g4)
    #pragma unroll
    for (int nt = 0; nt < 3; ++nt) {
      size_t nrow = (size_t)(g4 * 96 + n0 + nt * 16 + lr) * 96;
      #pragma unroll
      for (int ks = 0; ks < 3; ++ks) {
        ga[g4][nt] = __builtin_amdgcn_mfma_f32_16x16x32_bf16(
            gf[ks], ld8(&wihb[nrow + ks * 32 + lq * 8]), ga[g4][nt], 0, 0, 0);
        ga[g4][nt] = __builtin_amdgcn_mfma_f32_16x16x32_bf16(
            hin[ks], ld8(&whhb[nrow + ks * 32 + lq * 8]), ga[g4][nt], 0, 0, 0);
      }
    }
  #pragma unroll
  for (int nt = 0; nt < 3; ++nt) {
    int col = n0 + nt * 16 + lr;
    float bvi = bih[col] + bhh[col];
    float bvf = bih[96 + col] + bhh[96 + col];
    float bvg = bih[192 + col] + bhh[192 + col];
    float bvo = bih[288 + col] + bhh[288 + col];
    #pragma unroll
    for (int r = 0; r < 4; ++r) {
      int m = m0 + lq * 4 + r;
      size_t idx = (size_t)m * 96 + col;
      float gi = ga[0][nt][r] + bvi;
      float gfv = ga[1][nt][r] + bvf;
      float gg = ga[2][nt][r] + bvg;
      float go = ga[3][nt][r] + bvo;
      float si = 1.f / (1.f + expf(-gi));
      float sf = 1.f / (1.f + expf(-gfv));
      float so = 1.f / (1.f + expf(-go));
      float tg = tanhf(gg);
      float cn = sf * c[idx] + si * tg;
      c[idx] = cn;
      float ho = so * tanhf(cn);
      Hout[idx] = __float2bfloat16(ho);
      x1[(lq * 4 + r) * 100 + col] = ho;
    }
  }
  __syncthreads();
  bf16x8 hf[3];
  xbuf_frag(x1, lr, lq, nullptr, 0.f, nullptr, 0, hf);   // new H frags

  // ---- P_next = H @ wfn^T + bias_fn ----
  if (doP) {
    #pragma unroll
    for (int ph = 0; ph < 2; ++ph) {
      float* xb = ph ? x1 : x0;
      load_w48(wfnb + (size_t)ph * 96 * 96, 96, n0, lr, lq, wf); zacc3(acc); gemm48(hf, wf, acc);
      acc_store_cs(xb, acc, lr, lq, n0);
      __syncthreads();
      xbuf_frag(xb, lr, lq, bias_fn + ph * 96, 1.f, nullptr, 0, af);
      if (ch == 0) store_frag(&P[(size_t)(m0 + lr) * 192 + ph * 96], lq, af);
    }
  }

  // ---- r-MLP -> out ----
  load_w48(rw0b, 96, n0, lr, lq, wf); zacc3(acc); gemm48(hf, wf, acc);
  acc_store_cs(x0, acc, lr, lq, n0);
  __syncthreads();
  xbuf_frag(x0, lr, lq, r_b0, 1.f, nullptr, 1, af);
  load_w48(rw1b, 96, n0, lr, lq, wf); zacc3(acc); gemm48(af, wf, acc);
  acc_store_cs(x1, acc, lr, lq, n0);
  __syncthreads();
  xbuf_frag(x1, lr, lq, r_b1, 1.f, nullptr, 1, af);
  if (ch == 0) {
    bf16x8 w9[3];
    #pragma unroll
    for (int ks = 0; ks < 3; ++ks) {
      short8 s = {0, 0, 0, 0, 0, 0, 0, 0};
      if (lr < 9) s = *(const short8*)&rw2b[(size_t)lr * 96 + ks * 32 + lq * 8];
      w9[ks] = __builtin_bit_cast(bf16x8, s);
    }
    f32x4 a9 = (f32x4){0.f, 0.f, 0.f, 0.f};
    #pragma unroll
    for (int ks = 0; ks < 3; ++ks)
      a9 = __builtin_amdgcn_mfma_f32_16x16x32_bf16(af[ks], w9[ks], a9, 0, 0, 0);
    if (lr < 9) {
      float bb = r_b2[lr];
      #pragma unroll
      for (int r = 0; r < 4; ++r)
        outp[(size_t)(m0 + lq * 4 + r) * 9 + lr] = a9[r] + bb;
    }
  }
}

// ================= host side =================
extern "C" void kernel_launch(void* const* d_in, const int* in_sizes, int n_in,
                              void* d_out, int out_size, void* d_ws, size_t ws_size,
                              hipStream_t stream) {
  const float* embed   = (const float*)d_in[0];
  const float* in_w0   = (const float*)d_in[1];
  const float* in_b0   = (const float*)d_in[2];
  const float* in_w1   = (const float*)d_in[3];
  const float* in_b1   = (const float*)d_in[4];
  const float* in_w2   = (const float*)d_in[5];
  const float* in_b2   = (const float*)d_in[6];
  const float* f_w0    = (const float*)d_in[7];
  const float* f_b0    = (const float*)d_in[8];
  const float* f_w1    = (const float*)d_in[9];
  const float* f_b1    = (const float*)d_in[10];
  const float* f_w2    = (const float*)d_in[11];
  const float* f_b2    = (const float*)d_in[12];
  const float* g_w0    = (const float*)d_in[13];
  const float* g_b0    = (const float*)d_in[14];
  const float* g_w1    = (const float*)d_in[15];
  const float* g_b1    = (const float*)d_in[16];
  const float* g_w2    = (const float*)d_in[17];
  const float* g_b2    = (const float*)d_in[18];
  const float* wih     = (const float*)d_in[19];
  const float* whh     = (const float*)d_in[20];
  const float* bih     = (const float*)d_in[21];
  const float* bhh     = (const float*)d_in[22];
  const float* r_w0    = (const float*)d_in[23];
  const float* r_b0    = (const float*)d_in[24];
  const float* r_w1    = (const float*)d_in[25];
  const float* r_b1    = (const float*)d_in[26];
  const float* r_w2    = (const float*)d_in[27];
  const float* r_b2    = (const float*)d_in[28];
  const float* c0      = (const float*)d_in[29];
  const int*   grids   = (const int*)d_in[30];
  const int*   edges   = (const int*)d_in[31];

  float* out = (float*)d_out;
  const int iters = out_size / (BN * 9);   // = 4

  float* c    = (float*)d_ws;                        // BN*96 f32
  bf16* H0    = (bf16*)(c + (size_t)BN * 96);
  bf16* H1    = H0 + (size_t)BN * 96;
  bf16* Xg    = H1 + (size_t)BN * 96;
  bf16* P     = Xg + (size_t)BN * 96;                // BN*192
  bf16* Mb    = P  + (size_t)BN * 192;
  bf16* emb   = Mb + (size_t)BN * 96;                // BN*32
  bf16* w0pb  = emb + (size_t)BN * 32;               // 3072
  bf16* wfnb  = w0pb + 3072;                         // 18432
  bf16* inw1b = wfnb + 18432;
  bf16* inw2b = inw1b + 9216;
  bf16* fw1b  = inw2b + 9216;
  bf16* fw2b  = fw1b + 9216;
  bf16* gw0b  = fw2b + 9216;                         // 18432
  bf16* gw1b  = gw0b + 18432;
  bf16* gw2b  = gw1b + 9216;
  bf16* rw0b  = gw2b + 9216;
  bf16* rw1b  = rw0b + 9216;
  bf16* rw2b  = rw1b + 9216;                         // 864
  bf16* wihb  = rw2b + 864;                          // 36864
  bf16* whhb  = wihb + 36864;
  float* bias_fn = (float*)(whhb + 36864);           // 192 f32

  prep_k<<<dim3(144, 15), 256, 0, stream>>>(
      in_w1, in_w2, f_w1, f_w2, g_w1, g_w2, r_w0, r_w1, r_w2, wih, whh, g_w0,
      f_w0, in_w0, f_b0,
      inw1b, inw2b, fw1b, fw2b, gw1b, gw2b, rw0b, rw1b, rw2b, wihb, whhb, gw0b,
      wfnb, w0pb, bias_fn);
  embed_k<<<(BN * 32) / 256, 256, 0, stream>>>(embed, grids, emb);
  fused_in_k<<<BN / 32, 256, 0, stream>>>(emb, w0pb, in_b0, inw1b, in_b1, inw2b, in_b2,
                                          gw0b, g_b0, wfnb, bias_fn, H0, Xg, P);
  hipMemcpyAsync(c, c0, (size_t)BN * 96 * sizeof(float), hipMemcpyDeviceToDevice, stream);

  for (int it = 0; it < iters; ++it) {
    bf16* Hin  = (it & 1) ? H1 : H0;
    bf16* Hout = (it & 1) ? H0 : H1;
    edge_k<<<BN / 8, 256, 0, stream>>>(P, fw1b, f_b1, edges, fw2b, f_b2, Mb);
    fused_iter_k<<<BN / 32, 256, 0, stream>>>(
        Mb, gw0b, Xg, gw1b, g_b1, gw2b, g_b2,
        Hin, wihb, whhb, bih, bhh, c, Hout,
        wfnb, bias_fn, P, rw0b, r_b0, rw1b, r_b1, rw2b, r_b2,
        out + (size_t)it * BN * 9, it < iters - 1 ? 1 : 0);
  }
}